// Round 1
// baseline (1207.885 us; speedup 1.0000x reference)
//
#include <hip/hip_runtime.h>
#include <hip/hip_bf16.h>
#include <stdint.h>

#define BATCH  1024
#define DIM    1024
#define NKH    65536
#define HID    1024

// (BETA / sqrt(DIM)) * log2(e) = 0.25 * 1.4426950408889634
#define SC1 0.36067376022224085f

typedef __bf16 bf16x8 __attribute__((ext_vector_type(8)));
typedef float  f32x4  __attribute__((ext_vector_type(4)));

__device__ __forceinline__ unsigned short f2bf(float f) {
  union { float f; unsigned int u; } v; v.f = f;
  unsigned int r = v.u + 0x7fffu + ((v.u >> 16) & 1u);
  return (unsigned short)(r >> 16);
}
__device__ __forceinline__ float bf2f(unsigned short s) {
  union { unsigned int u; float f; } v; v.u = ((unsigned int)s) << 16;
  return v.f;
}
__device__ __forceinline__ unsigned int pk2(float lo, float hi) {
  union { __hip_bfloat162 h; unsigned int u; } v;
  v.h = __float22bfloat162_rn(make_float2(lo, hi));
  return v.u;
}

// ---------------------------------------------------------------------------
// values [65536,1024] fp32  ->  vT [1024,65536] bf16 (transposed, k-contig)
// ---------------------------------------------------------------------------
__global__ __launch_bounds__(256) void k_transpose_cast(
    const float* __restrict__ V, unsigned short* __restrict__ vT) {
  __shared__ float tile[64][65];  // +1 pad: conflict-free transposed reads
  const int t = threadIdx.x;
  const int nk0 = blockIdx.x * 64;
  const int j0  = blockIdx.y * 64;
  #pragma unroll
  for (int i = 0; i < 4; ++i) {
    int idx = t + i * 256;
    int row = idx >> 4, c4 = (idx & 15) << 2;
    float4 v = *(const float4*)(V + (size_t)(nk0 + row) * HID + (j0 + c4));
    tile[row][c4 + 0] = v.x; tile[row][c4 + 1] = v.y;
    tile[row][c4 + 2] = v.z; tile[row][c4 + 3] = v.w;
  }
  __syncthreads();
  const int q = t & 7, jj = t >> 3;
  #pragma unroll
  for (int i = 0; i < 2; ++i) {
    int j = jj + i * 32;
    uint4 o;
    o.x = pk2(tile[q*8+0][j], tile[q*8+1][j]);
    o.y = pk2(tile[q*8+2][j], tile[q*8+3][j]);
    o.z = pk2(tile[q*8+4][j], tile[q*8+5][j]);
    o.w = pk2(tile[q*8+6][j], tile[q*8+7][j]);
    *(uint4*)(vT + (size_t)(j0 + j) * NKH + (nk0 + q*8)) = o;
  }
}

// ---------------------------------------------------------------------------
// GEMM1: E[b,n] = exp2(SC1 * x[b,:]·keys[n,:])  (bf16 out)
// 128x128 tile, BK=32, 4 waves 2x2, fused fp32->bf16 staging cast.
// ---------------------------------------------------------------------------
__global__ __launch_bounds__(256) void k_gemm1_exp(
    const float* __restrict__ X, const float* __restrict__ Kp,
    unsigned short* __restrict__ E) {
  __shared__ __align__(16) unsigned short As[128 * 32];
  __shared__ __align__(16) unsigned short Bs[128 * 32];
  const int t = threadIdx.x;
  const int bm = blockIdx.x & 7, bn = blockIdx.x >> 3;  // bm fastest: 8 blocks share keys tile in L2
  const int m0 = bm << 7, n0 = bn << 7;
  const int rowS = t >> 1, half = t & 1;
  const float* ga = X  + (size_t)(m0 + rowS) * DIM + half * 16;
  const float* gb = Kp + (size_t)(n0 + rowS) * DIM + half * 16;
  unsigned short* wA = As + rowS * 32 + half * 16;
  unsigned short* wB = Bs + rowS * 32 + half * 16;
  const int lane = t & 63, wave = t >> 6;
  const int wm = (wave >> 1) << 6, wn = (wave & 1) << 6;
  const int r16 = lane & 15, quad = lane >> 4;
  f32x4 acc[4][4] = {};
  for (int k0 = 0; k0 < DIM; k0 += 32) {
    float4 a0 = *(const float4*)(ga + k0);
    float4 a1 = *(const float4*)(ga + k0 + 4);
    float4 a2 = *(const float4*)(ga + k0 + 8);
    float4 a3 = *(const float4*)(ga + k0 + 12);
    float4 b0 = *(const float4*)(gb + k0);
    float4 b1 = *(const float4*)(gb + k0 + 4);
    float4 b2 = *(const float4*)(gb + k0 + 8);
    float4 b3 = *(const float4*)(gb + k0 + 12);
    __syncthreads();
    uint4 w;
    w.x = pk2(a0.x, a0.y); w.y = pk2(a0.z, a0.w);
    w.z = pk2(a1.x, a1.y); w.w = pk2(a1.z, a1.w);
    *(uint4*)(wA) = w;
    w.x = pk2(a2.x, a2.y); w.y = pk2(a2.z, a2.w);
    w.z = pk2(a3.x, a3.y); w.w = pk2(a3.z, a3.w);
    *(uint4*)(wA + 8) = w;
    w.x = pk2(b0.x, b0.y); w.y = pk2(b0.z, b0.w);
    w.z = pk2(b1.x, b1.y); w.w = pk2(b1.z, b1.w);
    *(uint4*)(wB) = w;
    w.x = pk2(b2.x, b2.y); w.y = pk2(b2.z, b2.w);
    w.z = pk2(b3.x, b3.y); w.w = pk2(b3.z, b3.w);
    *(uint4*)(wB + 8) = w;
    __syncthreads();
    bf16x8 af[4], bfr[4];
    #pragma unroll
    for (int mi = 0; mi < 4; ++mi)
      af[mi] = *(const bf16x8*)(As + (wm + mi*16 + r16) * 32 + quad * 8);
    #pragma unroll
    for (int ni = 0; ni < 4; ++ni)
      bfr[ni] = *(const bf16x8*)(Bs + (wn + ni*16 + r16) * 32 + quad * 8);
    #pragma unroll
    for (int mi = 0; mi < 4; ++mi)
      #pragma unroll
      for (int ni = 0; ni < 4; ++ni)
        acc[mi][ni] = __builtin_amdgcn_mfma_f32_16x16x32_bf16(af[mi], bfr[ni], acc[mi][ni], 0, 0, 0);
  }
  // C/D layout (m89/m91 verified): col = lane&15, row = quad*4 + reg
  #pragma unroll
  for (int mi = 0; mi < 4; ++mi) {
    #pragma unroll
    for (int ni = 0; ni < 4; ++ni) {
      #pragma unroll
      for (int v = 0; v < 4; ++v) {
        int row = m0 + wm + mi*16 + quad*4 + v;
        int col = n0 + wn + ni*16 + r16;
        E[(size_t)row * NKH + col] = f2bf(exp2f(acc[mi][ni][v] * SC1));
      }
    }
  }
}

// ---------------------------------------------------------------------------
// r[b,h] = 1 / sum_k E[b, k*16+h]   (one block per batch row)
// ---------------------------------------------------------------------------
__global__ __launch_bounds__(256) void k_row_denom(
    const unsigned short* __restrict__ E, float* __restrict__ r) {
  __shared__ float acc16[16];
  const int t = threadIdx.x, b = blockIdx.x;
  if (t < 16) acc16[t] = 0.0f;
  __syncthreads();
  float s0=0,s1=0,s2=0,s3=0,s4=0,s5=0,s6=0,s7=0;
  const unsigned short* row = E + (size_t)b * NKH;
  for (int c = t; c < NKH / 8; c += 256) {
    uint4 u = *(const uint4*)(row + c * 8);
    s0 += bf2f((unsigned short)(u.x & 0xffff)); s1 += bf2f((unsigned short)(u.x >> 16));
    s2 += bf2f((unsigned short)(u.y & 0xffff)); s3 += bf2f((unsigned short)(u.y >> 16));
    s4 += bf2f((unsigned short)(u.z & 0xffff)); s5 += bf2f((unsigned short)(u.z >> 16));
    s6 += bf2f((unsigned short)(u.w & 0xffff)); s7 += bf2f((unsigned short)(u.w >> 16));
  }
  const int h0 = (t & 1) * 8;  // c parity == t parity (stride 256 even)
  atomicAdd(&acc16[h0 + 0], s0); atomicAdd(&acc16[h0 + 1], s1);
  atomicAdd(&acc16[h0 + 2], s2); atomicAdd(&acc16[h0 + 3], s3);
  atomicAdd(&acc16[h0 + 4], s4); atomicAdd(&acc16[h0 + 5], s5);
  atomicAdd(&acc16[h0 + 6], s6); atomicAdd(&acc16[h0 + 7], s7);
  __syncthreads();
  if (t < 16) r[b * 16 + t] = 1.0f / acc16[t];
}

// ---------------------------------------------------------------------------
// P = E * r[b, n%16]  in place (bf16)
// ---------------------------------------------------------------------------
__global__ __launch_bounds__(256) void k_scale(
    unsigned short* __restrict__ E, const float* __restrict__ r) {
  const int t = threadIdx.x, b = blockIdx.x;
  const int h0 = (t & 1) * 8;
  float rr[8];
  #pragma unroll
  for (int i = 0; i < 8; ++i) rr[i] = r[b * 16 + h0 + i];
  unsigned short* row = E + (size_t)b * NKH;
  for (int c = t; c < NKH / 8; c += 256) {
    uint4 u = *(uint4*)(row + c * 8);
    uint4 o;
    o.x = pk2(bf2f((unsigned short)(u.x & 0xffff)) * rr[0],
              bf2f((unsigned short)(u.x >> 16))    * rr[1]);
    o.y = pk2(bf2f((unsigned short)(u.y & 0xffff)) * rr[2],
              bf2f((unsigned short)(u.y >> 16))    * rr[3]);
    o.z = pk2(bf2f((unsigned short)(u.z & 0xffff)) * rr[4],
              bf2f((unsigned short)(u.z >> 16))    * rr[5]);
    o.w = pk2(bf2f((unsigned short)(u.w & 0xffff)) * rr[6],
              bf2f((unsigned short)(u.w >> 16))    * rr[7]);
    *(uint4*)(row + c * 8) = o;
  }
}

// ---------------------------------------------------------------------------
// GEMM2: out[b,j] += sum_n P[b,n] * vT[j,n]   split-K=16, atomic epilogue
// m97-style global_load_lds width-16 staging (both operands bf16).
// ---------------------------------------------------------------------------
__device__ __forceinline__ void gl2lds16(const void* g, void* l) {
  __builtin_amdgcn_global_load_lds(
      (const __attribute__((address_space(1))) void*)g,
      (__attribute__((address_space(3))) void*)l, 16, 0, 0);
}

__global__ __launch_bounds__(256) void k_gemm2(
    const unsigned short* __restrict__ P, const unsigned short* __restrict__ Vt,
    float* __restrict__ out) {
  __shared__ __align__(16) unsigned short As[128 * 32];
  __shared__ __align__(16) unsigned short Bs[128 * 32];
  const int t = threadIdx.x;
  const int bm = blockIdx.x & 7, bn = (blockIdx.x >> 3) & 7, sp = blockIdx.x >> 6;
  const int m0 = bm << 7, n0 = bn << 7;
  const size_t kb = (size_t)sp * (NKH / 16);
  const int lane = t & 63, wave = t >> 6;
  const int wm = (wave >> 1) << 6, wn = (wave & 1) << 6;
  const int r16 = lane & 15, quad = lane >> 4;
  const int srow = lane >> 2, kseg = (lane & 3) * 8;
  const int c0 = wave * 2, c1 = wave * 2 + 1;
  const unsigned short* gA0 = P  + (size_t)(m0 + c0*16 + srow) * NKH + kb + kseg;
  const unsigned short* gA1 = P  + (size_t)(m0 + c1*16 + srow) * NKH + kb + kseg;
  const unsigned short* gB0 = Vt + (size_t)(n0 + c0*16 + srow) * NKH + kb + kseg;
  const unsigned short* gB1 = Vt + (size_t)(n0 + c1*16 + srow) * NKH + kb + kseg;
  f32x4 acc[4][4] = {};
  for (int ks = 0; ks < NKH / 16; ks += 32) {
    __syncthreads();
    gl2lds16(gA0 + ks, As + c0 * 512);
    gl2lds16(gA1 + ks, As + c1 * 512);
    gl2lds16(gB0 + ks, Bs + c0 * 512);
    gl2lds16(gB1 + ks, Bs + c1 * 512);
    __syncthreads();  // compiler emits vmcnt(0) drain before s_barrier
    bf16x8 af[4], bfr[4];
    #pragma unroll
    for (int mi = 0; mi < 4; ++mi)
      af[mi] = *(const bf16x8*)(As + (wm + mi*16 + r16) * 32 + quad * 8);
    #pragma unroll
    for (int ni = 0; ni < 4; ++ni)
      bfr[ni] = *(const bf16x8*)(Bs + (wn + ni*16 + r16) * 32 + quad * 8);
    #pragma unroll
    for (int mi = 0; mi < 4; ++mi)
      #pragma unroll
      for (int ni = 0; ni < 4; ++ni)
        acc[mi][ni] = __builtin_amdgcn_mfma_f32_16x16x32_bf16(af[mi], bfr[ni], acc[mi][ni], 0, 0, 0);
  }
  #pragma unroll
  for (int mi = 0; mi < 4; ++mi) {
    #pragma unroll
    for (int ni = 0; ni < 4; ++ni) {
      #pragma unroll
      for (int v = 0; v < 4; ++v) {
        int row = m0 + wm + mi*16 + quad*4 + v;
        int col = n0 + wn + ni*16 + r16;
        unsafeAtomicAdd(&out[(size_t)row * HID + col], acc[mi][ni][v]);
      }
    }
  }
}

extern "C" void kernel_launch(void* const* d_in, const int* in_sizes, int n_in,
                              void* d_out, int out_size, void* d_ws, size_t ws_size,
                              hipStream_t stream) {
  (void)in_sizes; (void)n_in; (void)out_size; (void)ws_size;
  const float* x      = (const float*)d_in[0];
  const float* keys   = (const float*)d_in[1];
  const float* values = (const float*)d_in[2];
  float* out = (float*)d_out;

  // ws layout: E/P [1024*65536] bf16 (128MB) | vT [1024*65536] bf16 (128MB) | r [1024*16] f32
  unsigned short* E  = (unsigned short*)d_ws;
  unsigned short* vT = E + (size_t)BATCH * NKH;
  float* r = (float*)(vT + (size_t)HID * NKH);

  hipMemsetAsync(d_out, 0, (size_t)BATCH * HID * sizeof(float), stream);
  k_transpose_cast<<<dim3(NKH / 64, HID / 64), 256, 0, stream>>>(values, vT);
  k_gemm1_exp<<<(BATCH / 128) * (NKH / 128), 256, 0, stream>>>(x, keys, E);
  k_row_denom<<<BATCH, 256, 0, stream>>>(E, r);
  k_scale<<<BATCH, 256, 0, stream>>>(E, r);
  k_gemm2<<<(BATCH / 128) * (HID / 128) * 16, 256, 0, stream>>>(E, vT, out);
}

// Round 2
// 1137.558 us; speedup vs baseline: 1.0618x; 1.0618x over previous
//
#include <hip/hip_runtime.h>
#include <hip/hip_bf16.h>
#include <stdint.h>

#define BATCH  1024
#define DIM    1024
#define NKH    65536
#define HID    1024

// (BETA / sqrt(DIM)) * log2(e) = 0.25 * 1.4426950408889634
#define SC1 0.36067376022224085f

typedef __bf16 bf16x8 __attribute__((ext_vector_type(8)));
typedef float  f32x4  __attribute__((ext_vector_type(4)));

__device__ __forceinline__ unsigned short f2bf(float f) {
  union { float f; unsigned int u; } v; v.f = f;
  unsigned int r = v.u + 0x7fffu + ((v.u >> 16) & 1u);
  return (unsigned short)(r >> 16);
}
__device__ __forceinline__ float bf2f(unsigned short s) {
  union { unsigned int u; float f; } v; v.u = ((unsigned int)s) << 16;
  return v.f;
}
__device__ __forceinline__ unsigned int pk2(float lo, float hi) {
  union { __hip_bfloat162 h; unsigned int u; } v;
  v.h = __float22bfloat162_rn(make_float2(lo, hi));
  return v.u;
}
__device__ __forceinline__ void gl2lds16(const void* g, void* l) {
  __builtin_amdgcn_global_load_lds(
      (const __attribute__((address_space(1))) void*)g,
      (__attribute__((address_space(3))) void*)l, 16, 0, 0);
}

// ---------------------------------------------------------------------------
// fp32 -> bf16 cast, 8 elements/thread
// ---------------------------------------------------------------------------
__global__ __launch_bounds__(256) void k_cast(
    const float* __restrict__ s, unsigned short* __restrict__ d, int n8) {
  int i = blockIdx.x * 256 + threadIdx.x;
  if (i >= n8) return;
  float4 a = ((const float4*)s)[(size_t)i * 2];
  float4 b = ((const float4*)s)[(size_t)i * 2 + 1];
  uint4 o;
  o.x = pk2(a.x, a.y); o.y = pk2(a.z, a.w);
  o.z = pk2(b.x, b.y); o.w = pk2(b.z, b.w);
  ((uint4*)d)[i] = o;
}

// ---------------------------------------------------------------------------
// values [65536,1024] fp32  ->  vT [1024,65536] bf16 (transposed, k-contig)
// ---------------------------------------------------------------------------
__global__ __launch_bounds__(256) void k_transpose_cast(
    const float* __restrict__ V, unsigned short* __restrict__ vT) {
  __shared__ float tile[64][65];  // +1 pad: conflict-free transposed reads
  const int t = threadIdx.x;
  const int nk0 = blockIdx.x * 64;
  const int j0  = blockIdx.y * 64;
  #pragma unroll
  for (int i = 0; i < 4; ++i) {
    int idx = t + i * 256;
    int row = idx >> 4, c4 = (idx & 15) << 2;
    float4 v = *(const float4*)(V + (size_t)(nk0 + row) * HID + (j0 + c4));
    tile[row][c4 + 0] = v.x; tile[row][c4 + 1] = v.y;
    tile[row][c4 + 2] = v.z; tile[row][c4 + 3] = v.w;
  }
  __syncthreads();
  const int q = t & 7, jj = t >> 3;
  #pragma unroll
  for (int i = 0; i < 2; ++i) {
    int j = jj + i * 32;
    uint4 o;
    o.x = pk2(tile[q*8+0][j], tile[q*8+1][j]);
    o.y = pk2(tile[q*8+2][j], tile[q*8+3][j]);
    o.z = pk2(tile[q*8+4][j], tile[q*8+5][j]);
    o.w = pk2(tile[q*8+6][j], tile[q*8+7][j]);
    *(uint4*)(vT + (size_t)(j0 + j) * NKH + (nk0 + q*8)) = o;
  }
}

// ---------------------------------------------------------------------------
// GEMM1: E[b,n] = exp2(SC1 * x[b,:]·keys[n,:])  (bf16 in, bf16 out)
// m97 structure: global_load_lds width-16, 128x128 tile, BK=32, 4 waves 2x2.
// ---------------------------------------------------------------------------
__global__ __launch_bounds__(256) void k_gemm1_exp(
    const unsigned short* __restrict__ Xb, const unsigned short* __restrict__ Kb,
    unsigned short* __restrict__ E) {
  __shared__ __align__(16) unsigned short As[128 * 32];
  __shared__ __align__(16) unsigned short Bs[128 * 32];
  const int t = threadIdx.x;
  const int bm = blockIdx.x & 7, bn = blockIdx.x >> 3;  // bm fastest: 8 blocks share B-tile
  const int m0 = bm << 7, n0 = bn << 7;
  const int lane = t & 63, wave = t >> 6;
  const int wm = (wave >> 1) << 6, wn = (wave & 1) << 6;
  const int r16 = lane & 15, quad = lane >> 4;
  const int srow = lane >> 2, kseg = (lane & 3) * 8;
  const int c0 = wave * 2, c1 = wave * 2 + 1;
  const unsigned short* gA0 = Xb + (size_t)(m0 + c0*16 + srow) * DIM + kseg;
  const unsigned short* gA1 = Xb + (size_t)(m0 + c1*16 + srow) * DIM + kseg;
  const unsigned short* gB0 = Kb + (size_t)(n0 + c0*16 + srow) * DIM + kseg;
  const unsigned short* gB1 = Kb + (size_t)(n0 + c1*16 + srow) * DIM + kseg;
  f32x4 acc[4][4] = {};
  for (int ks = 0; ks < DIM; ks += 32) {
    __syncthreads();
    gl2lds16(gA0 + ks, As + c0 * 512);
    gl2lds16(gA1 + ks, As + c1 * 512);
    gl2lds16(gB0 + ks, Bs + c0 * 512);
    gl2lds16(gB1 + ks, Bs + c1 * 512);
    __syncthreads();
    bf16x8 af[4], bfr[4];
    #pragma unroll
    for (int mi = 0; mi < 4; ++mi)
      af[mi] = *(const bf16x8*)(As + (wm + mi*16 + r16) * 32 + quad * 8);
    #pragma unroll
    for (int ni = 0; ni < 4; ++ni)
      bfr[ni] = *(const bf16x8*)(Bs + (wn + ni*16 + r16) * 32 + quad * 8);
    #pragma unroll
    for (int mi = 0; mi < 4; ++mi)
      #pragma unroll
      for (int ni = 0; ni < 4; ++ni)
        acc[mi][ni] = __builtin_amdgcn_mfma_f32_16x16x32_bf16(af[mi], bfr[ni], acc[mi][ni], 0, 0, 0);
  }
  // C/D layout: col = lane&15, row = quad*4 + reg
  #pragma unroll
  for (int mi = 0; mi < 4; ++mi) {
    #pragma unroll
    for (int ni = 0; ni < 4; ++ni) {
      #pragma unroll
      for (int v = 0; v < 4; ++v) {
        int row = m0 + wm + mi*16 + quad*4 + v;
        int col = n0 + wn + ni*16 + r16;
        E[(size_t)row * NKH + col] = f2bf(exp2f(acc[mi][ni][v] * SC1));
      }
    }
  }
}

// ---------------------------------------------------------------------------
// r[b,h] = 1 / sum_k E[b, k*16+h]   (one block per batch row)
// ---------------------------------------------------------------------------
__global__ __launch_bounds__(256) void k_row_denom(
    const unsigned short* __restrict__ E, float* __restrict__ r) {
  __shared__ float acc16[16];
  const int t = threadIdx.x, b = blockIdx.x;
  if (t < 16) acc16[t] = 0.0f;
  __syncthreads();
  float s0=0,s1=0,s2=0,s3=0,s4=0,s5=0,s6=0,s7=0;
  const unsigned short* row = E + (size_t)b * NKH;
  for (int c = t; c < NKH / 8; c += 256) {
    uint4 u = *(const uint4*)(row + c * 8);
    s0 += bf2f((unsigned short)(u.x & 0xffff)); s1 += bf2f((unsigned short)(u.x >> 16));
    s2 += bf2f((unsigned short)(u.y & 0xffff)); s3 += bf2f((unsigned short)(u.y >> 16));
    s4 += bf2f((unsigned short)(u.z & 0xffff)); s5 += bf2f((unsigned short)(u.z >> 16));
    s6 += bf2f((unsigned short)(u.w & 0xffff)); s7 += bf2f((unsigned short)(u.w >> 16));
  }
  const int h0 = (t & 1) * 8;  // c parity == t parity (stride 256 even)
  atomicAdd(&acc16[h0 + 0], s0); atomicAdd(&acc16[h0 + 1], s1);
  atomicAdd(&acc16[h0 + 2], s2); atomicAdd(&acc16[h0 + 3], s3);
  atomicAdd(&acc16[h0 + 4], s4); atomicAdd(&acc16[h0 + 5], s5);
  atomicAdd(&acc16[h0 + 6], s6); atomicAdd(&acc16[h0 + 7], s7);
  __syncthreads();
  if (t < 16) r[b * 16 + t] = 1.0f / acc16[t];
}

// ---------------------------------------------------------------------------
// P = E * r[b, n%16]  in place (bf16)
// ---------------------------------------------------------------------------
__global__ __launch_bounds__(256) void k_scale(
    unsigned short* __restrict__ E, const float* __restrict__ r) {
  const int t = threadIdx.x, b = blockIdx.x;
  const int h0 = (t & 1) * 8;
  float rr[8];
  #pragma unroll
  for (int i = 0; i < 8; ++i) rr[i] = r[b * 16 + h0 + i];
  unsigned short* row = E + (size_t)b * NKH;
  for (int c = t; c < NKH / 8; c += 256) {
    uint4 u = *(uint4*)(row + c * 8);
    uint4 o;
    o.x = pk2(bf2f((unsigned short)(u.x & 0xffff)) * rr[0],
              bf2f((unsigned short)(u.x >> 16))    * rr[1]);
    o.y = pk2(bf2f((unsigned short)(u.y & 0xffff)) * rr[2],
              bf2f((unsigned short)(u.y >> 16))    * rr[3]);
    o.z = pk2(bf2f((unsigned short)(u.z & 0xffff)) * rr[4],
              bf2f((unsigned short)(u.z >> 16))    * rr[5]);
    o.w = pk2(bf2f((unsigned short)(u.w & 0xffff)) * rr[6],
              bf2f((unsigned short)(u.w >> 16))    * rr[7]);
    *(uint4*)(row + c * 8) = o;
  }
}

// ---------------------------------------------------------------------------
// GEMM2: out[b,j] += sum_n P[b,n] * vT[j,n]   split-K=16, atomic epilogue
// ---------------------------------------------------------------------------
__global__ __launch_bounds__(256) void k_gemm2(
    const unsigned short* __restrict__ P, const unsigned short* __restrict__ Vt,
    float* __restrict__ out) {
  __shared__ __align__(16) unsigned short As[128 * 32];
  __shared__ __align__(16) unsigned short Bs[128 * 32];
  const int t = threadIdx.x;
  const int bm = blockIdx.x & 7, bn = (blockIdx.x >> 3) & 7, sp = blockIdx.x >> 6;
  const int m0 = bm << 7, n0 = bn << 7;
  const size_t kb = (size_t)sp * (NKH / 16);
  const int lane = t & 63, wave = t >> 6;
  const int wm = (wave >> 1) << 6, wn = (wave & 1) << 6;
  const int r16 = lane & 15, quad = lane >> 4;
  const int srow = lane >> 2, kseg = (lane & 3) * 8;
  const int c0 = wave * 2, c1 = wave * 2 + 1;
  const unsigned short* gA0 = P  + (size_t)(m0 + c0*16 + srow) * NKH + kb + kseg;
  const unsigned short* gA1 = P  + (size_t)(m0 + c1*16 + srow) * NKH + kb + kseg;
  const unsigned short* gB0 = Vt + (size_t)(n0 + c0*16 + srow) * NKH + kb + kseg;
  const unsigned short* gB1 = Vt + (size_t)(n0 + c1*16 + srow) * NKH + kb + kseg;
  f32x4 acc[4][4] = {};
  for (int ks = 0; ks < NKH / 16; ks += 32) {
    __syncthreads();
    gl2lds16(gA0 + ks, As + c0 * 512);
    gl2lds16(gA1 + ks, As + c1 * 512);
    gl2lds16(gB0 + ks, Bs + c0 * 512);
    gl2lds16(gB1 + ks, Bs + c1 * 512);
    __syncthreads();
    bf16x8 af[4], bfr[4];
    #pragma unroll
    for (int mi = 0; mi < 4; ++mi)
      af[mi] = *(const bf16x8*)(As + (wm + mi*16 + r16) * 32 + quad * 8);
    #pragma unroll
    for (int ni = 0; ni < 4; ++ni)
      bfr[ni] = *(const bf16x8*)(Bs + (wn + ni*16 + r16) * 32 + quad * 8);
    #pragma unroll
    for (int mi = 0; mi < 4; ++mi)
      #pragma unroll
      for (int ni = 0; ni < 4; ++ni)
        acc[mi][ni] = __builtin_amdgcn_mfma_f32_16x16x32_bf16(af[mi], bfr[ni], acc[mi][ni], 0, 0, 0);
  }
  #pragma unroll
  for (int mi = 0; mi < 4; ++mi) {
    #pragma unroll
    for (int ni = 0; ni < 4; ++ni) {
      #pragma unroll
      for (int v = 0; v < 4; ++v) {
        int row = m0 + wm + mi*16 + quad*4 + v;
        int col = n0 + wn + ni*16 + r16;
        unsafeAtomicAdd(&out[(size_t)row * HID + col], acc[mi][ni][v]);
      }
    }
  }
}

extern "C" void kernel_launch(void* const* d_in, const int* in_sizes, int n_in,
                              void* d_out, int out_size, void* d_ws, size_t ws_size,
                              hipStream_t stream) {
  (void)in_sizes; (void)n_in; (void)out_size; (void)ws_size;
  const float* x      = (const float*)d_in[0];
  const float* keys   = (const float*)d_in[1];
  const float* values = (const float*)d_in[2];
  float* out = (float*)d_out;

  // ws layout: E/P [1024*65536] bf16 | B2 [65536*1024] bf16 (Kb, later vT) |
  //            Xb [1024*1024] bf16 | r [1024*16] f32      (~270 MB total)
  unsigned short* E  = (unsigned short*)d_ws;
  unsigned short* B2 = E + (size_t)BATCH * NKH;
  unsigned short* Xb = B2 + (size_t)NKH * DIM;
  float* r = (float*)(Xb + (size_t)BATCH * DIM);

  hipMemsetAsync(d_out, 0, (size_t)BATCH * HID * sizeof(float), stream);
  k_cast<<<(NKH * (DIM / 8) + 255) / 256, 256, 0, stream>>>(keys, B2, NKH * (DIM / 8));
  k_cast<<<(BATCH * (DIM / 8) + 255) / 256, 256, 0, stream>>>(x, Xb, BATCH * (DIM / 8));
  k_gemm1_exp<<<(BATCH / 128) * (NKH / 128), 256, 0, stream>>>(Xb, B2, E);
  k_row_denom<<<BATCH, 256, 0, stream>>>(E, r);
  k_scale<<<BATCH, 256, 0, stream>>>(E, r);
  // B2 now free (gemm1 done): reuse it for vT
  k_transpose_cast<<<dim3(NKH / 64, HID / 64), 256, 0, stream>>>(values, B2);
  k_gemm2<<<(BATCH / 128) * (HID / 128) * 16, 256, 0, stream>>>(E, B2, out);
}